// Round 6
// baseline (202.991 us; speedup 1.0000x reference)
//
#include <hip/hip_runtime.h>

// EmbedDNF: B=128, IN_F=256, HID=512, OUT=128, E=8 (fp32, e innermost)
//
// impl = 1 - w*(1-xnor) = A + x*Bv ; A = 1 - w*s ; Bv = 2*w*s - w
// H[b,h,e]   = prod_i (A[i,h,e] + x[b,i,e]*Bv[i,h,e])
// out[b,o,e] = 1 - prod_h (1 - dw[h,o,e]*H[b,h,e])
//
// ws: H [512][128][8] fp32 (2 MB, h-major: stage2 H-loads contiguous)
//
// R5 post-mortem: explicit pipelining spilled (VGPR cap 64 at 1024-thr
// blocks -> 71 MB scratch WRITE). R4 post-mortem: without pipelining, loads
// serialize at ~1600 cyc/iter (VALUBusy 12%). This round: 512-thr blocks,
// launch_bounds(512,2) => 256-VGPR cap (grid gives 2 waves/SIMD anyway),
// float4 tiles, fully-unrolled rotating load slots (depth 2 s1 / depth 4 s2).

#define LD4(p) (*(const float4*)(p))

static __device__ __forceinline__ float4 f4mul(float4 a, float4 b) {
    return make_float4(a.x*b.x, a.y*b.y, a.z*b.z, a.w*b.w);
}
static __device__ __forceinline__ float4 f4fma(float4 a, float4 b, float4 c) {
    return make_float4(fmaf(a.x,b.x,c.x), fmaf(a.y,b.y,c.y),
                       fmaf(a.z,b.z,c.z), fmaf(a.w,b.w,c.w));
}
static __device__ __forceinline__ float4 f4nfma1(float4 d, float4 h) {  // 1-d*h
    return make_float4(fmaf(-d.x,h.x,1.0f), fmaf(-d.y,h.y,1.0f),
                       fmaf(-d.z,h.z,1.0f), fmaf(-d.w,h.w,1.0f));
}

// ---------------------------------------------------------------------------
// Stage 1. Grid 256: hg = blk&15 (32 h, low bits -> ~1 MB w/s slice per XCD),
// bg = blk>>4 (8 b). Block 512 thr = 8 waves = 8 i-chunks of 32.
// Lane = hl(32 h) x eh(2 e-halves); thread tile 8b x 1h x 4e.
// Per K-step: w,s contiguous 1 KB wave-loads; 8 broadcast x loads; 76 VALU.
// Depth-2 rotating load slots (fully unrolled -> renamed, no movs).
// 8 i-partials combined via two-phase 32 KB LDS pass.
// ---------------------------------------------------------------------------
__global__ __launch_bounds__(512, 2) void k_stage1(
    const float* __restrict__ in,   // [128][256][8]
    const float* __restrict__ cw,   // [256][512][8]
    const float* __restrict__ cs,   // [256][512][8]
    float* __restrict__ H)          // ws: [512][128][8]
{
    __shared__ float lds[8 * 1024];          // 32 KB (half the partials per phase)
    const int t    = threadIdx.x;
    const int lane = t & 63;
    const int kc   = t >> 6;                 // i-chunk 0..7 (32 i each)
    const int eh   = lane & 1;
    const int hl   = lane >> 1;              // 0..31
    const int hg   = blockIdx.x & 15;        // low bits: XCD-sliced w/s
    const int bg   = blockIdx.x >> 4;
    const int b0   = bg * 8;
    const int h    = hg * 32 + hl;
    const int e0   = eh * 4;

    const float* pw = cw + (kc * 32) * 4096 + h * 8 + e0;
    const float* ps = cs + (kc * 32) * 4096 + h * 8 + e0;
    const float* px = in + b0 * 2048 + (kc * 32) * 8 + e0;

    float4 acc[8];
    #pragma unroll
    for (int b = 0; b < 8; ++b) acc[b] = make_float4(1.f, 1.f, 1.f, 1.f);

    // rotating slots, 2 K-steps deep
    float4 wb[2], sb[2], xb[2][8];
    #pragma unroll
    for (int j = 0; j < 2; ++j) {
        wb[j] = LD4(pw + j * 4096);
        sb[j] = LD4(ps + j * 4096);
        #pragma unroll
        for (int b = 0; b < 8; ++b) xb[j][b] = LD4(px + j * 8 + b * 2048);
    }

    #pragma unroll
    for (int ii = 0; ii < 32; ++ii) {
        const int sl = ii & 1;
        const float4 wc = wb[sl], sc = sb[sl];
        float4 xc[8];
        #pragma unroll
        for (int b = 0; b < 8; ++b) xc[b] = xb[sl][b];
        if (ii + 2 < 32) {                    // refill the slot we just drained
            wb[sl] = LD4(pw + (ii + 2) * 4096);
            sb[sl] = LD4(ps + (ii + 2) * 4096);
            #pragma unroll
            for (int b = 0; b < 8; ++b)
                xb[sl][b] = LD4(px + (ii + 2) * 8 + b * 2048);
        }
        const float4 p  = f4mul(wc, sc);
        const float4 A  = make_float4(1.f - p.x, 1.f - p.y, 1.f - p.z, 1.f - p.w);
        const float4 Bv = make_float4(p.x + p.x - wc.x, p.y + p.y - wc.y,
                                      p.z + p.z - wc.z, p.w + p.w - wc.w);
        #pragma unroll
        for (int b = 0; b < 8; ++b)
            acc[b] = f4mul(acc[b], f4fma(xc[b], Bv, A));
    }

    // two-phase combine (b 0-3, then b 4-7): 8 kc-partials x 1024 floats
    #pragma unroll
    for (int phase = 0; phase < 2; ++phase) {
        if (phase) __syncthreads();          // protect previous phase's reads
        #pragma unroll
        for (int b = 0; b < 4; ++b)
            *(float4*)&lds[kc * 1024 + b * 256 + hl * 8 + e0] = acc[phase * 4 + b];
        __syncthreads();
        if (t < 256) {
            const int o4 = t * 4;            // [0,1024): b'*256 + hl'*8 + e'
            float4 m = LD4(&lds[o4]);
            #pragma unroll
            for (int c = 1; c < 8; ++c) m = f4mul(m, LD4(&lds[c * 1024 + o4]));
            const int bq  = (o4 >> 8) + phase * 4;
            const int rem = o4 & 255;        // hl'*8 + e'
            *(float4*)(H + ((hg * 32 + (rem >> 3)) * 128 + b0 + bq) * 8 + (rem & 7)) = m;
        }
    }
}

// ---------------------------------------------------------------------------
// Stage 2. Grid 256: og = blk&15 (8 o, low bits -> ~512 KB dw slice per XCD),
// bg = blk>>4 (8 b). Block 512 thr = 8 waves = 8 h-chunks of 64.
// Lane = bl(8 b) x op(4 o-pairs) x eh(2); thread tile 1b x 2o x 4e.
// Per K-step: 1 contiguous H load (256 B) + 2 dw loads; 16 VALU.
// Depth-4 rotating slots (VALU/step only 64 cyc/SIMD -> need 4 in flight).
// ---------------------------------------------------------------------------
__global__ __launch_bounds__(512, 2) void k_stage2(
    const float* __restrict__ dw,   // [512][128][8]
    const float* __restrict__ H,    // ws: [512][128][8]
    float* __restrict__ out)        // [128][128][8]
{
    __shared__ float lds[8 * 512];           // 16 KB
    const int t    = threadIdx.x;
    const int lane = t & 63;
    const int kc   = t >> 6;                 // h-chunk 0..7 (64 h each)
    const int eh   = lane & 1;
    const int op   = (lane >> 1) & 3;
    const int bl   = lane >> 3;              // 0..7
    const int og   = blockIdx.x & 15;        // low bits: XCD-sliced dw
    const int bg   = blockIdx.x >> 4;
    const int b    = bg * 8 + bl;
    const int o0   = og * 8 + op * 2;
    const int e0   = eh * 4;

    const float* ph = H  + (kc * 64) * 1024 + b * 8 + e0;
    const float* pd = dw + (kc * 64) * 1024 + o0 * 8 + e0;

    float4 acc0 = make_float4(1.f, 1.f, 1.f, 1.f);
    float4 acc1 = acc0;

    float4 hb[4], d0b[4], d1b[4];
    #pragma unroll
    for (int j = 0; j < 4; ++j) {
        hb[j]  = LD4(ph + j * 1024);
        d0b[j] = LD4(pd + j * 1024);
        d1b[j] = LD4(pd + j * 1024 + 8);
    }

    #pragma unroll
    for (int ii = 0; ii < 64; ++ii) {
        const int sl = ii & 3;
        const float4 hc = hb[sl], d0 = d0b[sl], d1 = d1b[sl];
        if (ii + 4 < 64) {
            hb[sl]  = LD4(ph + (ii + 4) * 1024);
            d0b[sl] = LD4(pd + (ii + 4) * 1024);
            d1b[sl] = LD4(pd + (ii + 4) * 1024 + 8);
        }
        acc0 = f4mul(acc0, f4nfma1(d0, hc));
        acc1 = f4mul(acc1, f4nfma1(d1, hc));
    }

    const int base = kc * 512 + bl * 64 + (op * 2) * 8 + e0;
    *(float4*)&lds[base]     = acc0;
    *(float4*)&lds[base + 8] = acc1;
    __syncthreads();

    // 512 outputs / 512 threads; partial idx == output idx == t
    float m = lds[t];
    #pragma unroll
    for (int c = 1; c < 8; ++c) m *= lds[c * 512 + t];
    out[(bg * 8 + (t >> 6)) * 1024 + (og * 8 + ((t >> 3) & 7)) * 8 + (t & 7)] = 1.0f - m;
}

extern "C" void kernel_launch(void* const* d_in, const int* in_sizes, int n_in,
                              void* d_out, int out_size, void* d_ws, size_t ws_size,
                              hipStream_t stream)
{
    const float* in = (const float*)d_in[0];   // [128][256][8]
    const float* cw = (const float*)d_in[1];   // [256][512][8]
    const float* cs = (const float*)d_in[2];   // [256][512][8]
    const float* dw = (const float*)d_in[3];   // [512][128][8]
    float* outp = (float*)d_out;               // [128][128][8]
    float* H    = (float*)d_ws;                // 2 MB used

    k_stage1<<<256, 512, 0, stream>>>(in, cw, cs, H);
    k_stage2<<<256, 512, 0, stream>>>(dw, H, outp);
}

// Round 7
// 97.261 us; speedup vs baseline: 2.0871x; 2.0871x over previous
//
#include <hip/hip_runtime.h>

// EmbedDNF: B=128, IN_F=256, HID=512, OUT=128, E=8 (fp32, e innermost)
//
// impl = 1 - w*(1-xnor) = A + x*Bv ; A = 1 - w*s ; Bv = 2*w*s - w
// H[b,h,e]   = prod_i (A[i,h,e] + x[b,i,e]*Bv[i,h,e])
// out[b,o,e] = 1 - prod_h (1 - dw[h,o,e]*H[b,h,e])
//
// R4-R6 lesson: per-wave VMEM batching can't be forced from HIP source
// (explicit pipelines spill; naive loops serialize on 8 broadcast streams).
// m97 pattern instead: stage the reused/broadcast operand (x, H) in LDS with
// immediate-offset ds_reads; keep exactly 1-2 streaming VMEM loads per step;
// MLP comes from 16 waves/CU. Cross-block K-split partials go to global
// (P1: 4-way i-split of stage1, combined in stage2's prologue;
//  P2: 8-way h-split of stage2, combined + 1-x in k_comb2).
//
// ws: P1 [4][512][128][8] fp32 @ 0        (8 MB)
//     P2 [8][128][128][8] fp32 @ 2097152  (4 MB)

#define LD4(p) (*(const float4*)(p))

static __device__ __forceinline__ float4 f4mul(float4 a, float4 b) {
    return make_float4(a.x*b.x, a.y*b.y, a.z*b.z, a.w*b.w);
}
static __device__ __forceinline__ float4 f4fma(float4 a, float4 b, float4 c) {
    return make_float4(fmaf(a.x,b.x,c.x), fmaf(a.y,b.y,c.y),
                       fmaf(a.z,b.z,c.z), fmaf(a.w,b.w,c.w));
}
static __device__ __forceinline__ float4 f4nfma1(float4 d, float4 h) {  // 1-d*h
    return make_float4(fmaf(-d.x,h.x,1.0f), fmaf(-d.y,h.y,1.0f),
                       fmaf(-d.z,h.z,1.0f), fmaf(-d.w,h.w,1.0f));
}

// ---------------------------------------------------------------------------
// Stage 1. Grid 1024 = hg16 (32 h, low bits: XCD L2 slicing) x bg16 (8 b) x
// ks4 (64 i). Block 256 = 4 waves = 4 i-subchunks of 16. Lane = eh2 x hl32.
// Prologue: x-tile [8 b][64 i][8 e] (16 KB) -> LDS, coalesced.
// Step: 2 streaming VMEM (w,s: contiguous 1 KB wave-loads, ptr bump) +
// 8 ds_read_b128 (immediate offsets, 2 addrs/wave broadcast) + ~76 VALU.
// kc-partials combined in LDS (region reused from x-tile); ks-partials -> P1.
// ---------------------------------------------------------------------------
__global__ __launch_bounds__(256, 4) void k_stage1(
    const float* __restrict__ in,   // [128][256][8]
    const float* __restrict__ cw,   // [256][512][8]
    const float* __restrict__ cs,   // [256][512][8]
    float* __restrict__ P1)         // ws: [4][512][128][8]
{
    __shared__ float lds[8192];              // 32 KB: x-tile [0,4096) then combine
    const int t    = threadIdx.x;
    const int lane = t & 63;
    const int kc   = t >> 6;                 // 0..3
    const int eh   = lane & 1;
    const int hl   = lane >> 1;              // 0..31
    const int hg   = blockIdx.x & 15;
    const int bg   = (blockIdx.x >> 4) & 15;
    const int ks   = blockIdx.x >> 8;        // 0..3
    const int b0   = bg * 8;
    const int h    = hg * 32 + hl;
    const int e0   = eh * 4;

    // stage x[b0:+8][ks*64:+64][0:8] -> lds (layout [b][il][e]), coalesced
    {
        float4* xs4 = (float4*)lds;
        #pragma unroll
        for (int k = 0; k < 4; ++k) {
            const int f4  = t + k * 256;     // 0..1023
            const int b   = f4 >> 7;
            const int col = f4 & 127;        // float4 within 512 B row
            xs4[b * 128 + col] = LD4(in + (b0 + b) * 2048 + ks * 512 + col * 4);
        }
    }
    __syncthreads();

    const int i0 = (ks * 4 + kc) * 16;
    const float* pw = cw + i0 * 4096 + h * 8 + e0;
    const float* ps = cs + i0 * 4096 + h * 8 + e0;
    const float* xbase = lds + kc * 128 + e0;   // + b*512 + ii*8 (immediates)

    float4 acc[8];
    #pragma unroll
    for (int b = 0; b < 8; ++b) acc[b] = make_float4(1.f, 1.f, 1.f, 1.f);

    #pragma unroll
    for (int ii = 0; ii < 16; ++ii) {
        const float4 wv = LD4(pw);
        const float4 sv = LD4(ps);
        pw += 4096; ps += 4096;
        const float4 p  = f4mul(wv, sv);
        const float4 A  = make_float4(1.f - p.x, 1.f - p.y, 1.f - p.z, 1.f - p.w);
        const float4 Bv = make_float4(fmaf(2.f, p.x, -wv.x), fmaf(2.f, p.y, -wv.y),
                                      fmaf(2.f, p.z, -wv.z), fmaf(2.f, p.w, -wv.w));
        #pragma unroll
        for (int b = 0; b < 8; ++b) {
            const float4 xv = LD4(xbase + b * 512 + ii * 8);
            acc[b] = f4mul(acc[b], f4fma(xv, Bv, A));
        }
    }

    __syncthreads();                         // x-tile dead; reuse lds
    #pragma unroll
    for (int b = 0; b < 8; ++b)
        *(float4*)&lds[kc * 2048 + b * 256 + hl * 8 + e0] = acc[b];
    __syncthreads();

    {   // combine 4 kc; one (b,h) row of 8 e per thread; 32 B global store
        const int bq  = t >> 5;
        const int hl2 = t & 31;
        const int base = bq * 256 + hl2 * 8;
        float4 m0 = LD4(&lds[base]);
        float4 m1 = LD4(&lds[base + 4]);
        #pragma unroll
        for (int c = 1; c < 4; ++c) {
            m0 = f4mul(m0, LD4(&lds[c * 2048 + base]));
            m1 = f4mul(m1, LD4(&lds[c * 2048 + base + 4]));
        }
        float* q = P1 + ks * 524288 + (hg * 32 + hl2) * 1024 + (b0 + bq) * 8;
        *(float4*)q = m0;
        *(float4*)(q + 4) = m1;
    }
}

// ---------------------------------------------------------------------------
// Stage 2. Grid 512 = og4 (32 o, low bits: 512 KB dw slice/XCD) x bg16 (8 b)
// x ks8 (64 h). Block 256 = 4 waves = 4 h-subchunks of 16. Lane = eh2 x ol32.
// Prologue: H-tile [64 h][8 b][8 e] (16 KB) = product of 4 P1 partials -> LDS.
// Step: 1 streaming VMEM (dw: contiguous 1 KB wave-load) + 8 immediate-offset
// ds_reads + 64 VALU. kc-partials combined in LDS; ks-partials -> P2.
// ---------------------------------------------------------------------------
__global__ __launch_bounds__(256, 4) void k_stage2(
    const float* __restrict__ dw,   // [512][128][8]
    const float* __restrict__ P1,   // ws: [4][512][128][8]
    float* __restrict__ P2)         // ws: [8][128][128][8]
{
    __shared__ float lds[8192];              // 32 KB: H-tile [0,4096) then combine
    const int t    = threadIdx.x;
    const int lane = t & 63;
    const int kc   = t >> 6;                 // 0..3
    const int eh   = lane & 1;
    const int ol   = lane >> 1;              // 0..31
    const int og   = blockIdx.x & 3;
    const int bg   = (blockIdx.x >> 2) & 15;
    const int ks   = blockIdx.x >> 6;        // 0..7
    const int b0   = bg * 8;
    const int o    = og * 32 + ol;
    const int e0   = eh * 4;
    const int h0   = ks * 64;

    // H-tile: product of the 4 i-split partials, layout [hl][b][e]
    {
        float4* ht4 = (float4*)lds;
        #pragma unroll
        for (int k = 0; k < 4; ++k) {
            const int f4  = t + k * 256;     // 0..1023
            const int hl  = f4 >> 4;
            const int rem = f4 & 15;         // b*2 + eq
            const float* q = P1 + (h0 + hl) * 1024 + b0 * 8 + rem * 4;
            float4 m = LD4(q);
            m = f4mul(m, LD4(q + 524288));
            m = f4mul(m, LD4(q + 1048576));
            m = f4mul(m, LD4(q + 1572864));
            ht4[f4] = m;
        }
    }
    __syncthreads();

    const float* pd = dw + (h0 + kc * 16) * 1024 + o * 8 + e0;
    const float* hbase = lds + kc * 1024 + e0;  // + ii*64 + b*8 (immediates)

    float4 acc[8];
    #pragma unroll
    for (int b = 0; b < 8; ++b) acc[b] = make_float4(1.f, 1.f, 1.f, 1.f);

    #pragma unroll
    for (int ii = 0; ii < 16; ++ii) {
        const float4 dv = LD4(pd);
        pd += 1024;
        #pragma unroll
        for (int b = 0; b < 8; ++b) {
            const float4 hv = LD4(hbase + ii * 64 + b * 8);
            acc[b] = f4mul(acc[b], f4nfma1(dv, hv));
        }
    }

    __syncthreads();                         // H-tile dead; reuse lds
    #pragma unroll
    for (int b = 0; b < 8; ++b)
        *(float4*)&lds[kc * 2048 + b * 256 + ol * 8 + e0] = acc[b];
    __syncthreads();

    {   // combine 4 kc; one (b,o) row of 8 e per thread
        const int bq  = t >> 5;
        const int ol2 = t & 31;
        const int base = bq * 256 + ol2 * 8;
        float4 m0 = LD4(&lds[base]);
        float4 m1 = LD4(&lds[base + 4]);
        #pragma unroll
        for (int c = 1; c < 4; ++c) {
            m0 = f4mul(m0, LD4(&lds[c * 2048 + base]));
            m1 = f4mul(m1, LD4(&lds[c * 2048 + base + 4]));
        }
        float* q = P2 + ks * 131072 + (b0 + bq) * 1024 + (og * 32 + ol2) * 8;
        *(float4*)q = m0;
        *(float4*)(q + 4) = m1;
    }
}

// ---------------------------------------------------------------------------
// Final: out = 1 - prod over the 8 h-split partials. 0.5 MB out, 4 MB read.
// ---------------------------------------------------------------------------
__global__ __launch_bounds__(256, 4) void k_comb2(
    const float* __restrict__ P2,   // ws: [8][128][128][8]
    float* __restrict__ out)        // [128][128][8]
{
    const int idx4 = blockIdx.x * 256 + threadIdx.x;   // 0..32767
    float4 m = LD4(P2 + idx4 * 4);
    #pragma unroll
    for (int c = 1; c < 8; ++c)
        m = f4mul(m, LD4(P2 + c * 131072 + idx4 * 4));
    const float4 r = make_float4(1.f - m.x, 1.f - m.y, 1.f - m.z, 1.f - m.w);
    *(float4*)(out + idx4 * 4) = r;
}

extern "C" void kernel_launch(void* const* d_in, const int* in_sizes, int n_in,
                              void* d_out, int out_size, void* d_ws, size_t ws_size,
                              hipStream_t stream)
{
    const float* in = (const float*)d_in[0];   // [128][256][8]
    const float* cw = (const float*)d_in[1];   // [256][512][8]
    const float* cs = (const float*)d_in[2];   // [256][512][8]
    const float* dw = (const float*)d_in[3];   // [512][128][8]
    float* outp = (float*)d_out;               // [128][128][8]
    float* P1   = (float*)d_ws;                // 8 MB
    float* P2   = (float*)d_ws + 2097152;      // 4 MB

    k_stage1<<<1024, 256, 0, stream>>>(in, cw, cs, P1);
    k_stage2<<<512, 256, 0, stream>>>(dw, P1, P2);
    k_comb2<<<128, 256, 0, stream>>>(P2, outp);
}